// Round 4
// baseline (1641.799 us; speedup 1.0000x reference)
//
#include <hip/hip_runtime.h>
#include <cstdint>
#include <cstddef>

#define B_N   32768
#define D_DIM 512
#define NC_N  64
#define NP    4224      /* 4096 (skewed w_t) + 64 (w_z) + 8 (g_u) + 8 (g_v) + 48 pad */
#define KP    1536      /* [zh|zh|zl] . [wh|wl|wh] f16 split, K=3*512 */
#define KT_N  24        /* KP/64 */
#define TEPS  1e-3f
#define SC1   0x1.0p-22f  /* undo 2^11 * 2^11 input scaling */

typedef unsigned short u16;
typedef _Float16 f16;
typedef __attribute__((ext_vector_type(8))) _Float16 f16x8;
typedef __attribute__((ext_vector_type(4))) float f32x4;

__device__ __forceinline__ u16 h_of(float x) { f16 h = (f16)x; return *reinterpret_cast<u16*>(&h); }
__device__ __forceinline__ float f_of_h(u16 u) { f16 h = *reinterpret_cast<f16*>(&u); return (float)h; }
__device__ __forceinline__ float rdlane(float x, int k) {
    return __int_as_float(__builtin_amdgcn_readlane(__float_as_int(x), k));
}
// fast reciprocal: v_rcp_f32 + 1 Newton step (~2e-7 rel; LU slop fixed by f64 refinement)
__device__ __forceinline__ float frcp(float x) {
    float r = __builtin_amdgcn_rcpf(x);
    return r * fmaf(-x, r, 2.0f);
}

// split x*2048 into f16 hi + f16 lo (both normal-range for our data)
__device__ __forceinline__ void split2(float x, u16& h, u16& l) {
    float s = x * 2048.0f;           // exact
    h = h_of(s);
    l = h_of(s - f_of_h(h));
}

// ---------------- prep: B' rows -> [NP][1536] f16 = [wh|wl|wh]
// rows 0..4095: SKEWED transport weights: skw[i*64+j] = 0.25*(w_t[j*64+i] - w_t[i*64+j])
//   so the GEMM directly emits R[i][j] = (cI - S)[i][j] off-diagonal (diag exactly 0).
// rows 4096..4159: w_z ; 4160..4167: g_u ; 4168..4175: g_v ; rest 0.
__global__ __launch_bounds__(256) void prep_w_kernel(
    const float* __restrict__ wt, const float* __restrict__ wz,
    const float* __restrict__ gu, const float* __restrict__ gv,
    u16* __restrict__ dst)
{
    int t = blockIdx.x * 256 + threadIdx.x;         // NP*128 threads, 4 floats each
    if (t >= NP * 128) return;
    int row = t >> 7;
    int c4  = (t & 127) << 2;
    float4 v = make_float4(0.f, 0.f, 0.f, 0.f);
    if (row < 4096) {
        int i = row >> 6, j = row & 63;
        float4 a  = *(const float4*)(wt + (size_t)row * 512 + c4);
        float4 at = *(const float4*)(wt + (size_t)(j * 64 + i) * 512 + c4);
        v.x = 0.25f * (at.x - a.x);
        v.y = 0.25f * (at.y - a.y);
        v.z = 0.25f * (at.z - a.z);
        v.w = 0.25f * (at.w - a.w);
    }
    else if (row < 4160)  v = *(const float4*)(wz + (size_t)(row - 4096) * 512 + c4);
    else if (row < 4168)  v = *(const float4*)(gu + (size_t)(row - 4160) * 512 + c4);
    else if (row < 4176)  v = *(const float4*)(gv + (size_t)(row - 4168) * 512 + c4);
    ushort4 hv, lv;
    split2(v.x, hv.x, lv.x); split2(v.y, hv.y, lv.y);
    split2(v.z, hv.z, lv.z); split2(v.w, hv.w, lv.w);
    u16* base = dst + (size_t)row * KP + c4;
    *(ushort4*)(base)        = hv;   // wh (pairs zh)
    *(ushort4*)(base + 512)  = lv;   // wl (pairs zh)
    *(ushort4*)(base + 1024) = hv;   // wh (pairs zl)
}

// ---------------- prep: z chunk -> [CB][1536] f16 = [zh|zh|zl]
__global__ __launch_bounds__(256) void prep_z_kernel(
    const float* __restrict__ z, u16* __restrict__ dst, int chunkStart, int CB)
{
    int t = blockIdx.x * 256 + threadIdx.x;
    if (t >= CB * 128) return;
    int row = t >> 7;
    int c4  = (t & 127) << 2;
    float4 v = *(const float4*)(z + (size_t)(chunkStart + row) * 512 + c4);
    ushort4 hv, lv;
    split2(v.x, hv.x, lv.x); split2(v.y, hv.y, lv.y);
    split2(v.z, hv.z, lv.z); split2(v.w, hv.w, lv.w);
    u16* base = dst + (size_t)row * KP + c4;
    *(ushort4*)(base)        = hv;   // zh
    *(ushort4*)(base + 512)  = hv;   // zh (cross block)
    *(ushort4*)(base + 1024) = lv;   // zl
}

// ---------------- GEMM: C[CB][NP] f32 = (A[CB][KP] * B[NP][KP]^T) * 2^-22
// 128x128 tile, BK=64, 4 waves (2x2), 16x16x32 f16 MFMA, global_load_lds(16B)
__global__ __launch_bounds__(256) void gemm_kernel(
    const u16* __restrict__ A, const u16* __restrict__ Bw, float* __restrict__ C)
{
    __shared__ alignas(16) u16 As[128 * 64];
    __shared__ alignas(16) u16 Bs[128 * 64];
    const int t    = threadIdx.x;
    const int lane = t & 63;
    const int w    = t >> 6;
    const int wr   = w >> 1, wc = w & 1;
    const size_t m0 = (size_t)blockIdx.y * 128;
    const size_t n0 = (size_t)blockIdx.x * 128;

    const char* Ab = (const char*)A  + (m0 + (size_t)(t >> 3)) * (KP * 2) + (size_t)(t & 7) * 16;
    const char* Bb = (const char*)Bw + (n0 + (size_t)(t >> 3)) * (KP * 2) + (size_t)(t & 7) * 16;
    char* AsB = (char*)&As[0];
    char* BsB = (char*)&Bs[0];

    f32x4 acc[4][4];
    #pragma unroll
    for (int i = 0; i < 4; ++i)
        #pragma unroll
        for (int j = 0; j < 4; ++j)
            acc[i][j] = (f32x4){0.f, 0.f, 0.f, 0.f};

    const int lr = lane & 15;
    const int lk = (lane >> 4) * 8;

    #pragma unroll 1
    for (int kt = 0; kt < KT_N; ++kt) {
        __syncthreads();
        const size_t koff = (size_t)kt * 128;   // bytes within a row
        #pragma unroll
        for (int cc = 0; cc < 4; ++cc) {
            __builtin_amdgcn_global_load_lds(
                (const __attribute__((address_space(1))) unsigned int*)(Ab + (size_t)cc * (32 * KP * 2) + koff),
                (__attribute__((address_space(3))) unsigned int*)(AsB + cc * 4096 + w * 1024),
                16, 0, 0);
            __builtin_amdgcn_global_load_lds(
                (const __attribute__((address_space(1))) unsigned int*)(Bb + (size_t)cc * (32 * KP * 2) + koff),
                (__attribute__((address_space(3))) unsigned int*)(BsB + cc * 4096 + w * 1024),
                16, 0, 0);
        }
        asm volatile("s_waitcnt vmcnt(0)" ::: "memory");
        __syncthreads();
        #pragma unroll
        for (int kk = 0; kk < 64; kk += 32) {
            f16x8 af[4], bf[4];
            #pragma unroll
            for (int i = 0; i < 4; ++i) {
                af[i] = *(const f16x8*)&As[(wr * 64 + i * 16 + lr) * 64 + kk + lk];
                bf[i] = *(const f16x8*)&Bs[(wc * 64 + i * 16 + lr) * 64 + kk + lk];
            }
            #pragma unroll
            for (int i = 0; i < 4; ++i)
                #pragma unroll
                for (int j = 0; j < 4; ++j)
                    acc[i][j] = __builtin_amdgcn_mfma_f32_16x16x32_f16(af[i], bf[j], acc[i][j], 0, 0, 0);
        }
    }
    const int fq = lane >> 4;
    const int fr = lane & 15;
    #pragma unroll
    for (int i = 0; i < 4; ++i) {
        #pragma unroll
        for (int j = 0; j < 4; ++j) {
            size_t crow = m0 + (size_t)(wr * 64 + i * 16 + fq * 4);
            size_t ccol = n0 + (size_t)(wc * 64 + j * 16 + fr);
            #pragma unroll
            for (int r = 0; r < 4; ++r)
                C[(crow + r) * NP + ccol] = acc[i][j][r] * SC1;
        }
    }
}

// ---------------- per-sample Cayley solve + router
// 4 samples per 256-thread block (1 wave each, no LDS) for occupancy.
// M = cI - S; GEMM emitted S's negated-off-diag R row-contiguous (diag exactly 0),
// so c enters ONLY via the pivot. LU stores multipliers below diag and the
// RECIPROCAL pivot on the diag (kills all back-sub divides). One f64-residual
// refinement, v = 2c*y - q, scores = cq @ v, softmax/argmax.
__global__ __launch_bounds__(256, 8) void solve_kernel(
    const float* __restrict__ z, const float* __restrict__ bz,
    const float* __restrict__ gout, const float* __restrict__ cq,
    const float* __restrict__ G, float* __restrict__ rw, float* __restrict__ kc,
    int chunkStart)
{
    const int tid  = threadIdx.x;
    const int lane = tid & 63;
    const int sl   = (blockIdx.x << 2) + (tid >> 6);
    const size_t s = (size_t)chunkStart + sl;
    const float c  = 1.0f + TEPS;

    // ---- r2 = ||z||^2 (for tau)
    const float4* zr = (const float4*)(z + s * 512);
    float4 za = zr[lane];
    float4 zb = zr[64 + lane];
    float r2 = za.x * za.x + za.y * za.y + za.z * za.z + za.w * za.w
             + zb.x * zb.x + zb.y * zb.y + zb.z * zb.z + zb.w * zb.w;
    #pragma unroll
    for (int o = 32; o; o >>= 1) r2 += __shfl_xor(r2, o);

    const float* Grow = G + (size_t)sl * NP;
    const float* Rrow = Grow + (size_t)lane * 64;   // M row `lane` off-diag (diag==0)

    // ---- load M row `lane` (pure copy; no diagonal fixup needed)
    float m[64];
    #pragma unroll
    for (int j4 = 0; j4 < 16; ++j4) {
        float4 r4 = *(const float4*)(Rrow + j4 * 4);
        m[4 * j4 + 0] = r4.x;
        m[4 * j4 + 1] = r4.y;
        m[4 * j4 + 2] = r4.z;
        m[4 * j4 + 3] = r4.w;
    }

    // ---- q_k for k = lane (linear + bias + low-rank, from fused GEMM cols)
    float qv = bz[lane] + Grow[4096 + lane];
    #pragma unroll
    for (int r = 0; r < 8; ++r) {
        float a = Grow[4160 + r];   // zu_r (uniform)
        float b = Grow[4168 + r];   // zv_r (uniform)
        qv = fmaf(a * b, gout[r * 64 + lane], qv);
    }
    const float qorig = qv;

    // ---- LU (no pivoting; symmetric part cI > 0).
    // Below diag: multipliers. Diag: reciprocal pivot. Above diag: U.
    #pragma unroll
    for (int k = 0; k < 64; ++k) {
        float piv = rdlane(m[k], k) + c;        // +c only here (R diag == 0)
        float inv = frcp(piv);
        float f = (lane > k) ? m[k] * inv : 0.0f;
        qv = fmaf(-f, rdlane(qv, k), qv);
        m[k] = (lane > k) ? f : ((lane == k) ? inv : m[k]);
        #pragma unroll
        for (int j = k + 1; j < 64; ++j)
            m[j] = fmaf(-f, rdlane(m[j], k), m[j]);
    }

    // ---- back substitution (lane i ends with y_i); diag slot holds 1/piv
    float y = 0.0f;
    #pragma unroll
    for (int k = 63; k >= 0; --k) {
        float yk = rdlane(qv, k) * rdlane(m[k], k);
        y = (lane == k) ? yk : y;
        qv = (lane < k) ? fmaf(-m[k], yk, qv) : qv;
    }

    // ---- one refinement step: r = q - M*y in f64 (M re-read, L2-hot; diag via c*y)
    double rr_d = (double)qorig - (double)c * (double)y;
    #pragma unroll
    for (int j4 = 0; j4 < 16; ++j4) {
        float4 r4 = *(const float4*)(Rrow + j4 * 4);   // diag entry is exactly 0
        rr_d -= (double)r4.x * (double)rdlane(y, 4 * j4 + 0);
        rr_d -= (double)r4.y * (double)rdlane(y, 4 * j4 + 1);
        rr_d -= (double)r4.z * (double)rdlane(y, 4 * j4 + 2);
        rr_d -= (double)r4.w * (double)rdlane(y, 4 * j4 + 3);
    }
    float rf = (float)rr_d;
    #pragma unroll
    for (int k = 0; k < 64; ++k)
        rf = (lane > k) ? fmaf(-m[k], rdlane(rf, k), rf) : rf;
    float d = 0.0f;
    #pragma unroll
    for (int k = 63; k >= 0; --k) {
        float dk = rdlane(rf, k) * rdlane(m[k], k);
        d = (lane == k) ? dk : d;
        rf = (lane < k) ? fmaf(-m[k], dk, rf) : rf;
    }
    y += d;

    const float v = 2.0f * c * y - qorig;

    // ---- scores (lane = chart n), v broadcast via readlane
    float sc = 0.0f;
    const float4* cr = (const float4*)(cq + (size_t)lane * 64);
    #pragma unroll
    for (int j4 = 0; j4 < 16; ++j4) {
        float4 c4 = cr[j4];
        sc = fmaf(c4.x, rdlane(v, 4 * j4 + 0), sc);
        sc = fmaf(c4.y, rdlane(v, 4 * j4 + 1), sc);
        sc = fmaf(c4.z, rdlane(v, 4 * j4 + 2), sc);
        sc = fmaf(c4.w, rdlane(v, 4 * j4 + 3), sc);
    }

    // ---- softmax / argmax (tau uniform per sample -> argmax invariant to rcp err)
    float denom = fmaxf(1.0f - r2, 1e-3f);
    float tau   = fmaxf(4.0f * denom, 0.01f);   // sqrt(64)*denom/2
    float logit = sc * frcp(tau);
    float mx = logit;
    #pragma unroll
    for (int o = 32; o; o >>= 1) mx = fmaxf(mx, __shfl_xor(mx, o));
    float e = __expf(logit - mx);
    float sum = e;
    #pragma unroll
    for (int o = 32; o; o >>= 1) sum += __shfl_xor(sum, o);
    rw[s * 64 + lane] = e * frcp(sum);

    unsigned long long bal = __ballot(logit == mx);
    if (lane == 0) kc[s] = (float)(__ffsll(bal) - 1);
}

// ---------------- host orchestration
extern "C" void kernel_launch(void* const* d_in, const int* in_sizes, int n_in,
                              void* d_out, int out_size, void* d_ws, size_t ws_size,
                              hipStream_t stream)
{
    const float* z    = (const float*)d_in[0];
    const float* wz   = (const float*)d_in[1];
    const float* bz   = (const float*)d_in[2];
    const float* gout = (const float*)d_in[3];
    const float* gu   = (const float*)d_in[4];
    const float* gv   = (const float*)d_in[5];
    const float* cq   = (const float*)d_in[6];
    const float* wt   = (const float*)d_in[7];

    float* rw = (float*)d_out;
    float* kc = rw + (size_t)B_N * NC_N;

    const size_t whl_b = (size_t)NP * KP * 2;   // ~13 MB
    int CB = 128;
    const int cands[9] = {32768, 16384, 8192, 4096, 2048, 1024, 512, 256, 128};
    for (int i = 0; i < 9; ++i) {
        size_t need = whl_b + (size_t)cands[i] * ((size_t)KP * 2 + (size_t)NP * 4);
        if (need <= ws_size) { CB = cands[i]; break; }
    }

    u16*   w_hl = (u16*)d_ws;
    u16*   z_hl = (u16*)((char*)d_ws + whl_b);
    float* G    = (float*)((char*)d_ws + whl_b + (size_t)CB * KP * 2);

    prep_w_kernel<<<(NP * 128 + 255) / 256, 256, 0, stream>>>(wt, wz, gu, gv, w_hl);
    for (int cs = 0; cs < B_N; cs += CB) {
        prep_z_kernel<<<CB / 2, 256, 0, stream>>>(z, z_hl, cs, CB);
        gemm_kernel<<<dim3(NP / 128, CB / 128), 256, 0, stream>>>(z_hl, w_hl, G);
        solve_kernel<<<CB / 4, 256, 0, stream>>>(z, bz, gout, cq, G, rw, kc, cs);
    }
}

// Round 5
// 1133.075 us; speedup vs baseline: 1.4490x; 1.4490x over previous
//
#include <hip/hip_runtime.h>
#include <cstdint>
#include <cstddef>

#define B_N   32768
#define D_DIM 512
#define NC_N  64
#define NP    4224      /* 4096 (skewed w_t) + 64 (w_z) + 8 (g_u) + 8 (g_v) + 48 pad */
#define KP    1536      /* [zh|zh|zl] . [wh|wl|wh] f16 split, K=3*512 */
#define KT_N  24        /* KP/64 */
#define TEPS  1e-3f
#define SC1   0x1.0p-22f  /* undo 2^11 * 2^11 input scaling */

typedef unsigned short u16;
typedef _Float16 f16;
typedef __attribute__((ext_vector_type(8))) _Float16 f16x8;
typedef __attribute__((ext_vector_type(4))) float f32x4;

__device__ __forceinline__ u16 h_of(float x) { f16 h = (f16)x; return *reinterpret_cast<u16*>(&h); }
__device__ __forceinline__ float f_of_h(u16 u) { f16 h = *reinterpret_cast<f16*>(&u); return (float)h; }
__device__ __forceinline__ float rdlane(float x, int k) {
    return __int_as_float(__builtin_amdgcn_readlane(__float_as_int(x), k));
}
// fast reciprocal: v_rcp_f32 + 1 Newton step (~2e-7 rel; LU slop fixed by f64 refinement)
__device__ __forceinline__ float frcp(float x) {
    float r = __builtin_amdgcn_rcpf(x);
    return r * fmaf(-x, r, 2.0f);
}

// split x*2048 into f16 hi + f16 lo (both normal-range for our data)
__device__ __forceinline__ void split2(float x, u16& h, u16& l) {
    float s = x * 2048.0f;           // exact
    h = h_of(s);
    l = h_of(s - f_of_h(h));
}

// ---------------- prep: B' rows -> [NP][1536] f16 = [wh|wl|wh]
// rows 0..4095: SKEWED transport weights: skw[i*64+j] = 0.25*(w_t[j*64+i] - w_t[i*64+j])
//   so the GEMM directly emits R[i][j] = (cI - S)[i][j] off-diagonal (diag exactly 0).
// rows 4096..4159: w_z ; 4160..4167: g_u ; 4168..4175: g_v ; rest 0.
__global__ __launch_bounds__(256) void prep_w_kernel(
    const float* __restrict__ wt, const float* __restrict__ wz,
    const float* __restrict__ gu, const float* __restrict__ gv,
    u16* __restrict__ dst)
{
    int t = blockIdx.x * 256 + threadIdx.x;         // NP*128 threads, 4 floats each
    if (t >= NP * 128) return;
    int row = t >> 7;
    int c4  = (t & 127) << 2;
    float4 v = make_float4(0.f, 0.f, 0.f, 0.f);
    if (row < 4096) {
        int i = row >> 6, j = row & 63;
        float4 a  = *(const float4*)(wt + (size_t)row * 512 + c4);
        float4 at = *(const float4*)(wt + (size_t)(j * 64 + i) * 512 + c4);
        v.x = 0.25f * (at.x - a.x);
        v.y = 0.25f * (at.y - a.y);
        v.z = 0.25f * (at.z - a.z);
        v.w = 0.25f * (at.w - a.w);
    }
    else if (row < 4160)  v = *(const float4*)(wz + (size_t)(row - 4096) * 512 + c4);
    else if (row < 4168)  v = *(const float4*)(gu + (size_t)(row - 4160) * 512 + c4);
    else if (row < 4176)  v = *(const float4*)(gv + (size_t)(row - 4168) * 512 + c4);
    ushort4 hv, lv;
    split2(v.x, hv.x, lv.x); split2(v.y, hv.y, lv.y);
    split2(v.z, hv.z, lv.z); split2(v.w, hv.w, lv.w);
    u16* base = dst + (size_t)row * KP + c4;
    *(ushort4*)(base)        = hv;   // wh (pairs zh)
    *(ushort4*)(base + 512)  = lv;   // wl (pairs zh)
    *(ushort4*)(base + 1024) = hv;   // wh (pairs zl)
}

// ---------------- prep: z chunk -> [CB][1536] f16 = [zh|zh|zl]
__global__ __launch_bounds__(256) void prep_z_kernel(
    const float* __restrict__ z, u16* __restrict__ dst, int chunkStart, int CB)
{
    int t = blockIdx.x * 256 + threadIdx.x;
    if (t >= CB * 128) return;
    int row = t >> 7;
    int c4  = (t & 127) << 2;
    float4 v = *(const float4*)(z + (size_t)(chunkStart + row) * 512 + c4);
    ushort4 hv, lv;
    split2(v.x, hv.x, lv.x); split2(v.y, hv.y, lv.y);
    split2(v.z, hv.z, lv.z); split2(v.w, hv.w, lv.w);
    u16* base = dst + (size_t)row * KP + c4;
    *(ushort4*)(base)        = hv;   // zh
    *(ushort4*)(base + 512)  = hv;   // zh (cross block)
    *(ushort4*)(base + 1024) = lv;   // zl
}

// ---------------- GEMM: C[CB][NP] f32 = (A[CB][KP] * B[NP][KP]^T) * 2^-22
// 128x128 tile, BK=64, 4 waves (2x2), 16x16x32 f16 MFMA, global_load_lds(16B)
__global__ __launch_bounds__(256) void gemm_kernel(
    const u16* __restrict__ A, const u16* __restrict__ Bw, float* __restrict__ C)
{
    __shared__ alignas(16) u16 As[128 * 64];
    __shared__ alignas(16) u16 Bs[128 * 64];
    const int t    = threadIdx.x;
    const int lane = t & 63;
    const int w    = t >> 6;
    const int wr   = w >> 1, wc = w & 1;
    const size_t m0 = (size_t)blockIdx.y * 128;
    const size_t n0 = (size_t)blockIdx.x * 128;

    const char* Ab = (const char*)A  + (m0 + (size_t)(t >> 3)) * (KP * 2) + (size_t)(t & 7) * 16;
    const char* Bb = (const char*)Bw + (n0 + (size_t)(t >> 3)) * (KP * 2) + (size_t)(t & 7) * 16;
    char* AsB = (char*)&As[0];
    char* BsB = (char*)&Bs[0];

    f32x4 acc[4][4];
    #pragma unroll
    for (int i = 0; i < 4; ++i)
        #pragma unroll
        for (int j = 0; j < 4; ++j)
            acc[i][j] = (f32x4){0.f, 0.f, 0.f, 0.f};

    const int lr = lane & 15;
    const int lk = (lane >> 4) * 8;

    #pragma unroll 1
    for (int kt = 0; kt < KT_N; ++kt) {
        __syncthreads();
        const size_t koff = (size_t)kt * 128;   // bytes within a row
        #pragma unroll
        for (int cc = 0; cc < 4; ++cc) {
            __builtin_amdgcn_global_load_lds(
                (const __attribute__((address_space(1))) unsigned int*)(Ab + (size_t)cc * (32 * KP * 2) + koff),
                (__attribute__((address_space(3))) unsigned int*)(AsB + cc * 4096 + w * 1024),
                16, 0, 0);
            __builtin_amdgcn_global_load_lds(
                (const __attribute__((address_space(1))) unsigned int*)(Bb + (size_t)cc * (32 * KP * 2) + koff),
                (__attribute__((address_space(3))) unsigned int*)(BsB + cc * 4096 + w * 1024),
                16, 0, 0);
        }
        asm volatile("s_waitcnt vmcnt(0)" ::: "memory");
        __syncthreads();
        #pragma unroll
        for (int kk = 0; kk < 64; kk += 32) {
            f16x8 af[4], bf[4];
            #pragma unroll
            for (int i = 0; i < 4; ++i) {
                af[i] = *(const f16x8*)&As[(wr * 64 + i * 16 + lr) * 64 + kk + lk];
                bf[i] = *(const f16x8*)&Bs[(wc * 64 + i * 16 + lr) * 64 + kk + lk];
            }
            #pragma unroll
            for (int i = 0; i < 4; ++i)
                #pragma unroll
                for (int j = 0; j < 4; ++j)
                    acc[i][j] = __builtin_amdgcn_mfma_f32_16x16x32_f16(af[i], bf[j], acc[i][j], 0, 0, 0);
        }
    }
    const int fq = lane >> 4;
    const int fr = lane & 15;
    #pragma unroll
    for (int i = 0; i < 4; ++i) {
        #pragma unroll
        for (int j = 0; j < 4; ++j) {
            size_t crow = m0 + (size_t)(wr * 64 + i * 16 + fq * 4);
            size_t ccol = n0 + (size_t)(wc * 64 + j * 16 + fr);
            #pragma unroll
            for (int r = 0; r < 4; ++r)
                C[(crow + r) * NP + ccol] = acc[i][j][r] * SC1;
        }
    }
}

// ---------------- per-sample Cayley solve + router
// 4 samples per 256-thread block (1 wave each, no LDS).
// __launch_bounds__(256,4): 128 unified regs/wave (r3's proven scratch-free
// allocation: ~64 arch + AGPR). (256,8) = 64 regs spilled m[64] to scratch
// (r4: WRITE_SIZE 375 MB, 2610 GB/s) — never again.
// M = cI - S; GEMM emitted off-diag of -S row-contiguous (diag exactly 0),
// so c enters ONLY via the pivot. LU stores multipliers below diag and the
// RECIPROCAL pivot on the diag (kills all back-sub divides). One f64-residual
// refinement, v = 2c*y - q, scores = cq @ v, softmax/argmax.
__global__ __launch_bounds__(256, 4) void solve_kernel(
    const float* __restrict__ z, const float* __restrict__ bz,
    const float* __restrict__ gout, const float* __restrict__ cq,
    const float* __restrict__ G, float* __restrict__ rw, float* __restrict__ kc,
    int chunkStart)
{
    const int tid  = threadIdx.x;
    const int lane = tid & 63;
    const int sl   = (blockIdx.x << 2) + (tid >> 6);
    const size_t s = (size_t)chunkStart + sl;
    const float c  = 1.0f + TEPS;

    // ---- r2 = ||z||^2 (for tau)
    const float4* zr = (const float4*)(z + s * 512);
    float4 za = zr[lane];
    float4 zb = zr[64 + lane];
    float r2 = za.x * za.x + za.y * za.y + za.z * za.z + za.w * za.w
             + zb.x * zb.x + zb.y * zb.y + zb.z * zb.z + zb.w * zb.w;
    #pragma unroll
    for (int o = 32; o; o >>= 1) r2 += __shfl_xor(r2, o);

    const float* Grow = G + (size_t)sl * NP;
    const float* Rrow = Grow + (size_t)lane * 64;   // M row `lane` off-diag (diag==0)

    // ---- load M row `lane` (pure copy; diagonal fixup folded into pivot)
    float m[64];
    #pragma unroll
    for (int j4 = 0; j4 < 16; ++j4) {
        float4 r4 = *(const float4*)(Rrow + j4 * 4);
        m[4 * j4 + 0] = r4.x;
        m[4 * j4 + 1] = r4.y;
        m[4 * j4 + 2] = r4.z;
        m[4 * j4 + 3] = r4.w;
    }

    // ---- q_k for k = lane (linear + bias + low-rank, from fused GEMM cols)
    float qv = bz[lane] + Grow[4096 + lane];
    #pragma unroll
    for (int r = 0; r < 8; ++r) {
        float a = Grow[4160 + r];   // zu_r (uniform)
        float b = Grow[4168 + r];   // zv_r (uniform)
        qv = fmaf(a * b, gout[r * 64 + lane], qv);
    }
    const float qorig = qv;

    // ---- LU (no pivoting; symmetric part cI > 0).
    // Below diag: multipliers. Diag: reciprocal pivot. Above diag: U.
    #pragma unroll
    for (int k = 0; k < 64; ++k) {
        float piv = rdlane(m[k], k) + c;        // +c only here (R diag == 0)
        float inv = frcp(piv);
        float f = (lane > k) ? m[k] * inv : 0.0f;
        qv = fmaf(-f, rdlane(qv, k), qv);
        m[k] = (lane > k) ? f : ((lane == k) ? inv : m[k]);
        #pragma unroll
        for (int j = k + 1; j < 64; ++j)
            m[j] = fmaf(-f, rdlane(m[j], k), m[j]);
    }

    // ---- back substitution (lane i ends with y_i); diag slot holds 1/piv
    float y = 0.0f;
    #pragma unroll
    for (int k = 63; k >= 0; --k) {
        float yk = rdlane(qv, k) * rdlane(m[k], k);
        y = (lane == k) ? yk : y;
        qv = (lane < k) ? fmaf(-m[k], yk, qv) : qv;
    }

    // ---- one refinement step: r = q - M*y in f64 (M re-read, L2-hot; diag via c*y)
    double rr_d = (double)qorig - (double)c * (double)y;
    #pragma unroll
    for (int j4 = 0; j4 < 16; ++j4) {
        float4 r4 = *(const float4*)(Rrow + j4 * 4);   // diag entry is exactly 0
        rr_d -= (double)r4.x * (double)rdlane(y, 4 * j4 + 0);
        rr_d -= (double)r4.y * (double)rdlane(y, 4 * j4 + 1);
        rr_d -= (double)r4.z * (double)rdlane(y, 4 * j4 + 2);
        rr_d -= (double)r4.w * (double)rdlane(y, 4 * j4 + 3);
    }
    float rf = (float)rr_d;
    #pragma unroll
    for (int k = 0; k < 64; ++k)
        rf = (lane > k) ? fmaf(-m[k], rdlane(rf, k), rf) : rf;
    float d = 0.0f;
    #pragma unroll
    for (int k = 63; k >= 0; --k) {
        float dk = rdlane(rf, k) * rdlane(m[k], k);
        d = (lane == k) ? dk : d;
        rf = (lane < k) ? fmaf(-m[k], dk, rf) : rf;
    }
    y += d;

    const float v = 2.0f * c * y - qorig;

    // ---- scores (lane = chart n), v broadcast via readlane
    float sc = 0.0f;
    const float4* cr = (const float4*)(cq + (size_t)lane * 64);
    #pragma unroll
    for (int j4 = 0; j4 < 16; ++j4) {
        float4 c4 = cr[j4];
        sc = fmaf(c4.x, rdlane(v, 4 * j4 + 0), sc);
        sc = fmaf(c4.y, rdlane(v, 4 * j4 + 1), sc);
        sc = fmaf(c4.z, rdlane(v, 4 * j4 + 2), sc);
        sc = fmaf(c4.w, rdlane(v, 4 * j4 + 3), sc);
    }

    // ---- softmax / argmax (tau uniform per sample -> argmax invariant to rcp err)
    float denom = fmaxf(1.0f - r2, 1e-3f);
    float tau   = fmaxf(4.0f * denom, 0.01f);   // sqrt(64)*denom/2
    float logit = sc * frcp(tau);
    float mx = logit;
    #pragma unroll
    for (int o = 32; o; o >>= 1) mx = fmaxf(mx, __shfl_xor(mx, o));
    float e = __expf(logit - mx);
    float sum = e;
    #pragma unroll
    for (int o = 32; o; o >>= 1) sum += __shfl_xor(sum, o);
    rw[s * 64 + lane] = e * frcp(sum);

    unsigned long long bal = __ballot(logit == mx);
    if (lane == 0) kc[s] = (float)(__ffsll(bal) - 1);
}

// ---------------- host orchestration
extern "C" void kernel_launch(void* const* d_in, const int* in_sizes, int n_in,
                              void* d_out, int out_size, void* d_ws, size_t ws_size,
                              hipStream_t stream)
{
    const float* z    = (const float*)d_in[0];
    const float* wz   = (const float*)d_in[1];
    const float* bz   = (const float*)d_in[2];
    const float* gout = (const float*)d_in[3];
    const float* gu   = (const float*)d_in[4];
    const float* gv   = (const float*)d_in[5];
    const float* cq   = (const float*)d_in[6];
    const float* wt   = (const float*)d_in[7];

    float* rw = (float*)d_out;
    float* kc = rw + (size_t)B_N * NC_N;

    const size_t whl_b = (size_t)NP * KP * 2;   // ~13 MB
    int CB = 128;
    const int cands[9] = {32768, 16384, 8192, 4096, 2048, 1024, 512, 256, 128};
    for (int i = 0; i < 9; ++i) {
        size_t need = whl_b + (size_t)cands[i] * ((size_t)KP * 2 + (size_t)NP * 4);
        if (need <= ws_size) { CB = cands[i]; break; }
    }

    u16*   w_hl = (u16*)d_ws;
    u16*   z_hl = (u16*)((char*)d_ws + whl_b);
    float* G    = (float*)((char*)d_ws + whl_b + (size_t)CB * KP * 2);

    prep_w_kernel<<<(NP * 128 + 255) / 256, 256, 0, stream>>>(wt, wz, gu, gv, w_hl);
    for (int cs = 0; cs < B_N; cs += CB) {
        prep_z_kernel<<<CB / 2, 256, 0, stream>>>(z, z_hl, cs, CB);
        gemm_kernel<<<dim3(NP / 128, CB / 128), 256, 0, stream>>>(z_hl, w_hl, G);
        solve_kernel<<<CB / 4, 256, 0, stream>>>(z, bz, gout, cq, G, rw, kc, cs);
    }
}

// Round 6
// 970.163 us; speedup vs baseline: 1.6923x; 1.1679x over previous
//
#include <hip/hip_runtime.h>
#include <cstdint>
#include <cstddef>

#define B_N   32768
#define D_DIM 512
#define NC_N  64
#define NP    4224      /* 4096 (skewed w_t) + 64 (w_z) + 8 (g_u) + 8 (g_v) + 48 pad */
#define KP    1536      /* [zh|zh|zl] . [wh|wl|wh] f16 split, K=3*512 */
#define KT_N  24        /* KP/64 */
#define TEPS  1e-3f
#define SC1   0x1.0p-22f  /* undo 2^11 * 2^11 input scaling */

typedef unsigned short u16;
typedef _Float16 f16;
typedef __attribute__((ext_vector_type(8))) _Float16 f16x8;
typedef __attribute__((ext_vector_type(4))) float f32x4;

__device__ __forceinline__ u16 h_of(float x) { f16 h = (f16)x; return *reinterpret_cast<u16*>(&h); }
__device__ __forceinline__ float f_of_h(u16 u) { f16 h = *reinterpret_cast<f16*>(&u); return (float)h; }
__device__ __forceinline__ float rdlane(float x, int k) {
    return __int_as_float(__builtin_amdgcn_readlane(__float_as_int(x), k));
}
// fast reciprocal: v_rcp_f32 + 1 Newton step (~2e-7 rel; slop fixed by f64 refinement)
__device__ __forceinline__ float frcp(float x) {
    float r = __builtin_amdgcn_rcpf(x);
    return r * fmaf(-x, r, 2.0f);
}

// split x*2048 into f16 hi + f16 lo (both normal-range for our data)
__device__ __forceinline__ void split2(float x, u16& h, u16& l) {
    float s = x * 2048.0f;           // exact
    h = h_of(s);
    l = h_of(s - f_of_h(h));
}

// ---------------- prep: B' rows -> [NP][1536] f16 = [wh|wl|wh]
// rows 0..4095: SKEWED transport weights: skw[i*64+j] = 0.25*(w_t[j*64+i] - w_t[i*64+j])
//   so the GEMM directly emits R[i][j] = (cI - S)[i][j] off-diagonal (diag exactly 0).
// rows 4096..4159: w_z ; 4160..4167: g_u ; 4168..4175: g_v ; rest 0.
__global__ __launch_bounds__(256) void prep_w_kernel(
    const float* __restrict__ wt, const float* __restrict__ wz,
    const float* __restrict__ gu, const float* __restrict__ gv,
    u16* __restrict__ dst)
{
    int t = blockIdx.x * 256 + threadIdx.x;         // NP*128 threads, 4 floats each
    if (t >= NP * 128) return;
    int row = t >> 7;
    int c4  = (t & 127) << 2;
    float4 v = make_float4(0.f, 0.f, 0.f, 0.f);
    if (row < 4096) {
        int i = row >> 6, j = row & 63;
        float4 a  = *(const float4*)(wt + (size_t)row * 512 + c4);
        float4 at = *(const float4*)(wt + (size_t)(j * 64 + i) * 512 + c4);
        v.x = 0.25f * (at.x - a.x);
        v.y = 0.25f * (at.y - a.y);
        v.z = 0.25f * (at.z - a.z);
        v.w = 0.25f * (at.w - a.w);
    }
    else if (row < 4160)  v = *(const float4*)(wz + (size_t)(row - 4096) * 512 + c4);
    else if (row < 4168)  v = *(const float4*)(gu + (size_t)(row - 4160) * 512 + c4);
    else if (row < 4176)  v = *(const float4*)(gv + (size_t)(row - 4168) * 512 + c4);
    ushort4 hv, lv;
    split2(v.x, hv.x, lv.x); split2(v.y, hv.y, lv.y);
    split2(v.z, hv.z, lv.z); split2(v.w, hv.w, lv.w);
    u16* base = dst + (size_t)row * KP + c4;
    *(ushort4*)(base)        = hv;   // wh (pairs zh)
    *(ushort4*)(base + 512)  = lv;   // wl (pairs zh)
    *(ushort4*)(base + 1024) = hv;   // wh (pairs zl)
}

// ---------------- prep: z chunk -> [CB][1536] f16 = [zh|zh|zl]
__global__ __launch_bounds__(256) void prep_z_kernel(
    const float* __restrict__ z, u16* __restrict__ dst, int chunkStart, int CB)
{
    int t = blockIdx.x * 256 + threadIdx.x;
    if (t >= CB * 128) return;
    int row = t >> 7;
    int c4  = (t & 127) << 2;
    float4 v = *(const float4*)(z + (size_t)(chunkStart + row) * 512 + c4);
    ushort4 hv, lv;
    split2(v.x, hv.x, lv.x); split2(v.y, hv.y, lv.y);
    split2(v.z, hv.z, lv.z); split2(v.w, hv.w, lv.w);
    u16* base = dst + (size_t)row * KP + c4;
    *(ushort4*)(base)        = hv;   // zh
    *(ushort4*)(base + 512)  = hv;   // zh (cross block)
    *(ushort4*)(base + 1024) = lv;   // zl
}

// ---------------- GEMM: C[CB][NP] f32 = (A[CB][KP] * B[NP][KP]^T) * 2^-22
// 128x128 tile, BK=64, 4 waves (2x2), 16x16x32 f16 MFMA, global_load_lds(16B)
// + bijective XCD-aware workgroup swizzle (T1) for A-panel L2 locality.
__global__ __launch_bounds__(256) void gemm_kernel(
    const u16* __restrict__ A, const u16* __restrict__ Bw, float* __restrict__ C)
{
    __shared__ alignas(16) u16 As[128 * 64];
    __shared__ alignas(16) u16 Bs[128 * 64];
    const int t    = threadIdx.x;
    const int lane = t & 63;
    const int w    = t >> 6;
    const int wr   = w >> 1, wc = w & 1;

    // XCD swizzle: contiguous chunk of flat ids per XCD (only when nwg % 8 == 0)
    const int nwg = gridDim.x * gridDim.y;
    int flat = blockIdx.y * gridDim.x + blockIdx.x;
    if ((nwg & 7) == 0) {
        const int cpx = nwg >> 3;
        flat = (flat & 7) * cpx + (flat >> 3);
    }
    const int bx = flat % gridDim.x;
    const int by = flat / gridDim.x;
    const size_t m0 = (size_t)by * 128;
    const size_t n0 = (size_t)bx * 128;

    const char* Ab = (const char*)A  + (m0 + (size_t)(t >> 3)) * (KP * 2) + (size_t)(t & 7) * 16;
    const char* Bb = (const char*)Bw + (n0 + (size_t)(t >> 3)) * (KP * 2) + (size_t)(t & 7) * 16;
    char* AsB = (char*)&As[0];
    char* BsB = (char*)&Bs[0];

    f32x4 acc[4][4];
    #pragma unroll
    for (int i = 0; i < 4; ++i)
        #pragma unroll
        for (int j = 0; j < 4; ++j)
            acc[i][j] = (f32x4){0.f, 0.f, 0.f, 0.f};

    const int lr = lane & 15;
    const int lk = (lane >> 4) * 8;

    #pragma unroll 1
    for (int kt = 0; kt < KT_N; ++kt) {
        __syncthreads();
        const size_t koff = (size_t)kt * 128;   // bytes within a row
        #pragma unroll
        for (int cc = 0; cc < 4; ++cc) {
            __builtin_amdgcn_global_load_lds(
                (const __attribute__((address_space(1))) unsigned int*)(Ab + (size_t)cc * (32 * KP * 2) + koff),
                (__attribute__((address_space(3))) unsigned int*)(AsB + cc * 4096 + w * 1024),
                16, 0, 0);
            __builtin_amdgcn_global_load_lds(
                (const __attribute__((address_space(1))) unsigned int*)(Bb + (size_t)cc * (32 * KP * 2) + koff),
                (__attribute__((address_space(3))) unsigned int*)(BsB + cc * 4096 + w * 1024),
                16, 0, 0);
        }
        asm volatile("s_waitcnt vmcnt(0)" ::: "memory");
        __syncthreads();
        #pragma unroll
        for (int kk = 0; kk < 64; kk += 32) {
            f16x8 af[4], bf[4];
            #pragma unroll
            for (int i = 0; i < 4; ++i) {
                af[i] = *(const f16x8*)&As[(wr * 64 + i * 16 + lr) * 64 + kk + lk];
                bf[i] = *(const f16x8*)&Bs[(wc * 64 + i * 16 + lr) * 64 + kk + lk];
            }
            #pragma unroll
            for (int i = 0; i < 4; ++i)
                #pragma unroll
                for (int j = 0; j < 4; ++j)
                    acc[i][j] = __builtin_amdgcn_mfma_f32_16x16x32_f16(af[i], bf[j], acc[i][j], 0, 0, 0);
        }
    }
    const int fq = lane >> 4;
    const int fr = lane & 15;
    #pragma unroll
    for (int i = 0; i < 4; ++i) {
        #pragma unroll
        for (int j = 0; j < 4; ++j) {
            size_t crow = m0 + (size_t)(wr * 64 + i * 16 + fq * 4);
            size_t ccol = n0 + (size_t)(wc * 64 + j * 16 + fr);
            #pragma unroll
            for (int r = 0; r < 4; ++r)
                C[(crow + r) * NP + ccol] = acc[i][j][r] * SC1;
        }
    }
}

// ---------------- per-sample Cayley solve + router
// 4 samples per 256-thread block (1 wave each, no LDS).
// Plain __launch_bounds__(256): FULL register budget (r3's proven scratch-free
// allocation). Any min-waves clause caps unified regs and spills m[64]
// (r4: 375 MB, r5: 82 MB scratch writes) — never again.
// GAUSS-JORDAN (not LU): eliminate column k from ALL rows each step; M becomes
// diagonal -> y = qv * myinv, NO back-substitution. Multiplier column stored
// in the freed m[k] slot (pivot lane stores 0) so the refinement re-solve is a
// mask-free 64x(readlane+fma) sweep. One f64-residual refinement,
// v = u^T q = 2c*y - q, scores = cq @ v, softmax/argmax.
__global__ __launch_bounds__(256) void solve_kernel(
    const float* __restrict__ z, const float* __restrict__ bz,
    const float* __restrict__ gout, const float* __restrict__ cq,
    const float* __restrict__ G, float* __restrict__ rw, float* __restrict__ kc,
    int chunkStart)
{
    const int tid  = threadIdx.x;
    const int lane = tid & 63;
    const int sl   = (blockIdx.x << 2) + (tid >> 6);
    const size_t s = (size_t)chunkStart + sl;
    const float c  = 1.0f + TEPS;

    // ---- r2 = ||z||^2 (for tau)
    const float4* zr = (const float4*)(z + s * 512);
    float4 za = zr[lane];
    float4 zb = zr[64 + lane];
    float r2 = za.x * za.x + za.y * za.y + za.z * za.z + za.w * za.w
             + zb.x * zb.x + zb.y * zb.y + zb.z * zb.z + zb.w * zb.w;
    #pragma unroll
    for (int o = 32; o; o >>= 1) r2 += __shfl_xor(r2, o);

    const float* Grow = G + (size_t)sl * NP;
    const float* Rrow = Grow + (size_t)lane * 64;   // M row `lane` off-diag (diag==0)

    // ---- load M row `lane` (diagonal fixup folded into pivot)
    float m[64];
    #pragma unroll
    for (int j4 = 0; j4 < 16; ++j4) {
        float4 r4 = *(const float4*)(Rrow + j4 * 4);
        m[4 * j4 + 0] = r4.x;
        m[4 * j4 + 1] = r4.y;
        m[4 * j4 + 2] = r4.z;
        m[4 * j4 + 3] = r4.w;
    }

    // ---- q_k for k = lane (linear + bias + low-rank, from fused GEMM cols)
    float qv = bz[lane] + Grow[4096 + lane];
    #pragma unroll
    for (int r = 0; r < 8; ++r) {
        float a = Grow[4160 + r];   // zu_r (uniform)
        float b = Grow[4168 + r];   // zv_r (uniform)
        qv = fmaf(a * b, gout[r * 64 + lane], qv);
    }
    const float qorig = qv;

    // ---- Gauss-Jordan (no pivoting; symmetric part cI > 0)
    float myinv = 0.0f;
    #pragma unroll
    for (int k = 0; k < 64; ++k) {
        float piv = rdlane(m[k], k) + c;        // +c only here (R diag == 0)
        float inv = frcp(piv);
        bool isk = (lane == k);
        float f = isk ? 0.0f : m[k] * inv;
        myinv = isk ? inv : myinv;
        qv = fmaf(-f, rdlane(qv, k), qv);
        #pragma unroll
        for (int j = k + 1; j < 64; ++j)
            m[j] = fmaf(-f, rdlane(m[j], k), m[j]);
        m[k] = f;                               // column k zeroed: keep multiplier
    }
    float y = qv * myinv;

    // ---- one refinement step: r = q - M*y in f64 (M re-read, L2-hot; diag via c*y)
    double rr_d = (double)qorig - (double)c * (double)y;
    #pragma unroll
    for (int j4 = 0; j4 < 16; ++j4) {
        float4 r4 = *(const float4*)(Rrow + j4 * 4);   // diag entry is exactly 0
        rr_d -= (double)r4.x * (double)rdlane(y, 4 * j4 + 0);
        rr_d -= (double)r4.y * (double)rdlane(y, 4 * j4 + 1);
        rr_d -= (double)r4.z * (double)rdlane(y, 4 * j4 + 2);
        rr_d -= (double)r4.w * (double)rdlane(y, 4 * j4 + 3);
    }
    // re-apply the stored GJ ops to the residual (pivot slots hold 0 -> no masks)
    float rf = (float)rr_d;
    #pragma unroll
    for (int k = 0; k < 64; ++k)
        rf = fmaf(-m[k], rdlane(rf, k), rf);
    y = fmaf(rf, myinv, y);

    const float v = 2.0f * c * y - qorig;

    // ---- scores (lane = chart n), v broadcast via readlane
    float sc = 0.0f;
    const float4* cr = (const float4*)(cq + (size_t)lane * 64);
    #pragma unroll
    for (int j4 = 0; j4 < 16; ++j4) {
        float4 c4 = cr[j4];
        sc = fmaf(c4.x, rdlane(v, 4 * j4 + 0), sc);
        sc = fmaf(c4.y, rdlane(v, 4 * j4 + 1), sc);
        sc = fmaf(c4.z, rdlane(v, 4 * j4 + 2), sc);
        sc = fmaf(c4.w, rdlane(v, 4 * j4 + 3), sc);
    }

    // ---- softmax / argmax (tau uniform per sample -> argmax invariant to rcp err)
    float denom = fmaxf(1.0f - r2, 1e-3f);
    float tau   = fmaxf(4.0f * denom, 0.01f);   // sqrt(64)*denom/2
    float logit = sc * frcp(tau);
    float mx = logit;
    #pragma unroll
    for (int o = 32; o; o >>= 1) mx = fmaxf(mx, __shfl_xor(mx, o));
    float e = __expf(logit - mx);
    float sum = e;
    #pragma unroll
    for (int o = 32; o; o >>= 1) sum += __shfl_xor(sum, o);
    rw[s * 64 + lane] = e * frcp(sum);

    unsigned long long bal = __ballot(logit == mx);
    if (lane == 0) kc[s] = (float)(__ffsll(bal) - 1);
}

// ---------------- host orchestration
extern "C" void kernel_launch(void* const* d_in, const int* in_sizes, int n_in,
                              void* d_out, int out_size, void* d_ws, size_t ws_size,
                              hipStream_t stream)
{
    const float* z    = (const float*)d_in[0];
    const float* wz   = (const float*)d_in[1];
    const float* bz   = (const float*)d_in[2];
    const float* gout = (const float*)d_in[3];
    const float* gu   = (const float*)d_in[4];
    const float* gv   = (const float*)d_in[5];
    const float* cq   = (const float*)d_in[6];
    const float* wt   = (const float*)d_in[7];

    float* rw = (float*)d_out;
    float* kc = rw + (size_t)B_N * NC_N;

    const size_t whl_b = (size_t)NP * KP * 2;   // ~13 MB
    int CB = 128;
    const int cands[9] = {32768, 16384, 8192, 4096, 2048, 1024, 512, 256, 128};
    for (int i = 0; i < 9; ++i) {
        size_t need = whl_b + (size_t)cands[i] * ((size_t)KP * 2 + (size_t)NP * 4);
        if (need <= ws_size) { CB = cands[i]; break; }
    }

    u16*   w_hl = (u16*)d_ws;
    u16*   z_hl = (u16*)((char*)d_ws + whl_b);
    float* G    = (float*)((char*)d_ws + whl_b + (size_t)CB * KP * 2);

    prep_w_kernel<<<(NP * 128 + 255) / 256, 256, 0, stream>>>(wt, wz, gu, gv, w_hl);
    for (int cs = 0; cs < B_N; cs += CB) {
        prep_z_kernel<<<CB / 2, 256, 0, stream>>>(z, z_hl, cs, CB);
        gemm_kernel<<<dim3(NP / 128, CB / 128), 256, 0, stream>>>(z_hl, w_hl, G);
        solve_kernel<<<CB / 4, 256, 0, stream>>>(z, bz, gout, cq, G, rw, kc, cs);
    }
}